// Round 2
// baseline (838.921 us; speedup 1.0000x reference)
//
#include <hip/hip_runtime.h>
#include <hip/hip_bf16.h>

typedef __attribute__((ext_vector_type(4))) float f32x4;
typedef __attribute__((ext_vector_type(8))) short bf16x8;

__device__ __forceinline__ short f2bf(float x){
    __hip_bfloat16 h = __float2bfloat16(x);
    return __builtin_bit_cast(short, h);
}

// ---------------------------------------------------------------- prep: W2T bf16 [192][384]
__global__ void prep_w2t(const float* __restrict__ W2, short* __restrict__ W2T){
    int i = blockIdx.x*256 + threadIdx.x;            // i < 73728 exactly (288 blocks)
    int n = i/384, k = i%384;
    W2T[i] = f2bf(W2[k*192 + n]);
}

// ---------------------------------------------------------------- Aq = query@W1a, B = doc@W1b (fp32)
// blocks 0..255: 16 docs each;  blocks 256..257: 16 query rows each. 384 threads.
__global__ void ab_kernel(const float* __restrict__ doc, const float* __restrict__ query,
                          const float* __restrict__ W1, float* __restrict__ Bws,
                          float* __restrict__ Aq){
    __shared__ float lsrc[16*384];
    const int b = blockIdx.x, tid = threadIdx.x;
    const float* src; const float* w; float* out;
    if (b < 256){ int r0 = b*16;      src = doc   + r0*384; w = W1 + 384*384; out = Bws + r0*384; }
    else        { int r0 = (b-256)*16; src = query + r0*384; w = W1;           out = Aq  + r0*384; }
    #pragma unroll
    for (int i=0;i<4;i++){ int idx = tid + i*384;
        *(f32x4*)(lsrc + idx*4) = *(const f32x4*)(src + idx*4); }
    __syncthreads();
    float acc[16];
    #pragma unroll
    for (int d=0; d<16; d++) acc[d] = 0.0f;
    const int j = tid;
    #pragma unroll 2
    for (int k=0; k<384; k++){
        float wv = w[k*384 + j];                       // coalesced; lsrc reads broadcast (free)
        #pragma unroll
        for (int d=0; d<16; d++) acc[d] += lsrc[d*384 + k]*wv;
    }
    #pragma unroll
    for (int d=0; d<16; d++) out[d*384 + j] = acc[d];
}

// ---------------------------------------------------------------- dense scores + sparse copy
// 256 blocks x 256 thr; block handles 16 docs, all 32 q.
__global__ void dense_sparse_kernel(const float* __restrict__ query, const float* __restrict__ doc,
                                    const float* __restrict__ sparse, float* __restrict__ out_dense,
                                    float* __restrict__ out_sparse){
    __shared__ float ldsq[32*388];   // pad 388: bank stride 4 -> conflict-free reads
    __shared__ float ldsd[16*388];
    const int tid = threadIdx.x, d0 = blockIdx.x*16;
    #pragma unroll
    for (int i=0;i<12;i++){ int idx = tid + i*256; int row = idx/96, c4 = idx%96;
        *(f32x4*)(ldsq + row*388 + c4*4) = *(const f32x4*)(query + row*384 + c4*4); }
    #pragma unroll
    for (int i=0;i<6;i++){ int idx = tid + i*256; int row = idx/96, c4 = idx%96;
        *(f32x4*)(ldsd + row*388 + c4*4) = *(const f32x4*)(doc + (d0+row)*384 + c4*4); }
    __syncthreads();
    const int q = tid>>3, dg = tid&7;
    float acc0 = 0.0f, acc1 = 0.0f;
    #pragma unroll 4
    for (int k=0;k<384;k++){
        float qv = ldsq[q*388 + k];
        acc0 += qv*ldsd[dg*388 + k];
        acc1 += qv*ldsd[(dg+8)*388 + k];
    }
    out_dense[q*4096 + d0 + dg]     = acc0;
    out_dense[q*4096 + d0 + dg + 8] = acc1;
    // sparse passthrough: this block's 16 columns for all 32 q rows = 512 floats = 128 f32x4
    if (tid < 128){
        int qq = tid>>2, c4 = tid&3;
        *(f32x4*)(out_sparse + qq*4096 + d0 + c4*4) = *(const f32x4*)(sparse + qq*4096 + d0 + c4*4);
    }
}

// ---------------------------------------------------------------- main fused MLP kernel
// 256 blocks x 512 thr. W2T resident in LDS (padded rows of 392 bf16 = 784 B).
// Wave owns 16 rows per tile-iter; h1 built directly in MFMA A-fragment registers.
__global__ __launch_bounds__(512, 2)
void main_kernel(const float* __restrict__ Aq, const float* __restrict__ Bws,
                 const float* __restrict__ W1, const float* __restrict__ b1,
                 const float* __restrict__ b2, const float* __restrict__ W3,
                 const float* __restrict__ b3, const float* __restrict__ sparse,
                 const short* __restrict__ W2T, const float* __restrict__ dense_in,
                 float* __restrict__ out_final){
    __shared__ short lw[192*392];                    // 150,528 B (gfx950: 160 KB addressable)
    const int tid = threadIdx.x;
    // stage W2T: 9216 x 16B, pad rows 768B -> 784B
    #pragma unroll
    for (int i=0;i<18;i++){
        int idx = tid + i*512; int row = idx/48, seg = idx%48;
        *(f32x4*)((char*)lw + row*784 + seg*16) =
            *(const f32x4*)((const char*)W2T + row*768 + seg*16);
    }
    __syncthreads();                                 // only barrier in the kernel

    const int lane = tid & 63, w = tid >> 6;
    const int cl = lane & 15, quad = lane >> 4;
    float b2r[12], w3r[12];
    #pragma unroll
    for (int t=0;t<12;t++){ b2r[t] = b2[t*16 + cl]; w3r[t] = W3[t*16 + cl]; }
    const float b3v = b3[0];
    const float* w1c = W1 + 768*384;
    const float* w1d = W1 + 769*384;

    for (int t4=0; t4<4; t4++){
        const int R0 = blockIdx.x*512 + t4*128 + w*16;   // 16 consecutive rows, same doc
        const int dcol = R0 >> 5;
        const int q0 = R0 & 31;
        const int q = q0 + cl;                       // this lane's h1 row (A-frag m = lane&15)
        const float dsv = dense_in[q*4096 + dcol];
        const float ssv = sparse[q*4096 + dcol];

        // ---- layer 1: h1 in A-fragment layout: k = 32*g + quad*8 + j
        bf16x8 afrag[12];
        #pragma unroll
        for (int g=0; g<12; g++){
            const int k0 = g*32 + quad*8;
            const f32x4 a0  = *(const f32x4*)(Aq  + q*384 + k0);
            const f32x4 a1  = *(const f32x4*)(Aq  + q*384 + k0 + 4);
            const f32x4 bv0 = *(const f32x4*)(Bws + dcol*384 + k0);
            const f32x4 bv1 = *(const f32x4*)(Bws + dcol*384 + k0 + 4);
            const f32x4 wc0 = *(const f32x4*)(w1c + k0);
            const f32x4 wc1 = *(const f32x4*)(w1c + k0 + 4);
            const f32x4 wd0 = *(const f32x4*)(w1d + k0);
            const f32x4 wd1 = *(const f32x4*)(w1d + k0 + 4);
            const f32x4 bb0 = *(const f32x4*)(b1  + k0);
            const f32x4 bb1 = *(const f32x4*)(b1  + k0 + 4);
            bf16x8 fr;
            #pragma unroll
            for (int j=0;j<4;j++){
                float h = a0[j] + bv0[j] + bb0[j] + dsv*wc0[j] + ssv*wd0[j];
                fr[j] = f2bf(fmaxf(h, 0.0f));
            }
            #pragma unroll
            for (int j=0;j<4;j++){
                float h = a1[j] + bv1[j] + bb1[j] + dsv*wc1[j] + ssv*wd1[j];
                fr[4+j] = f2bf(fmaxf(h, 0.0f));
            }
            afrag[g] = fr;
        }

        // ---- layer 2: 12 ksteps x 12 n-tiles of mfma 16x16x32 bf16
        f32x4 acc[12];
        #pragma unroll
        for (int t=0;t<12;t++) acc[t] = (f32x4){0.f,0.f,0.f,0.f};
        #pragma unroll
        for (int s=0;s<12;s++){
            #pragma unroll
            for (int t=0;t<12;t++){
                // B-frag: n = 16t + cl, k = 32s + quad*8 .. +8 ; 16B-aligned, 2-way bank alias (free)
                const bf16x8 bfr = *(const bf16x8*)((const char*)lw + (t*16 + cl)*784 + s*64 + quad*16);
                acc[t] = __builtin_amdgcn_mfma_f32_16x16x32_bf16(afrag[s], bfr, acc[t], 0, 0, 0);
            }
        }

        // ---- layer 3 + sigmoid blend. D layout: col = lane&15 -> n, row = quad*4 + r
        float p[4] = {0.f,0.f,0.f,0.f};
        #pragma unroll
        for (int t=0;t<12;t++){
            #pragma unroll
            for (int r=0;r<4;r++)
                p[r] += fmaxf(acc[t][r] + b2r[t], 0.0f) * w3r[t];
        }
        #pragma unroll
        for (int m=1; m<16; m<<=1){
            #pragma unroll
            for (int r=0;r<4;r++) p[r] += __shfl_xor(p[r], m);
        }
        if (cl == 0){
            #pragma unroll
            for (int r=0;r<4;r++){
                int qq = q0 + quad*4 + r;
                float logit = p[r] + b3v;
                float wgt = 1.0f/(1.0f + __expf(-logit));
                float dd = dense_in[qq*4096 + dcol];
                float ss = sparse[qq*4096 + dcol];
                out_final[qq*4096 + dcol] = wgt*dd + (1.0f - wgt)*ss;
            }
        }
    }
}

// ---------------------------------------------------------------- launch
extern "C" void kernel_launch(void* const* d_in, const int* in_sizes, int n_in,
                              void* d_out, int out_size, void* d_ws, size_t ws_size,
                              hipStream_t stream){
    const float* query  = (const float*)d_in[0];
    const float* doc    = (const float*)d_in[1];
    const float* sparse = (const float*)d_in[2];
    const float* W1     = (const float*)d_in[3];
    const float* b1     = (const float*)d_in[4];
    const float* W2     = (const float*)d_in[5];
    const float* b2     = (const float*)d_in[6];
    const float* W3     = (const float*)d_in[7];
    const float* b3     = (const float*)d_in[8];

    float* out_final  = (float*)d_out;                 // [32,4096]
    float* out_dense  = (float*)d_out + 131072;        // [32,4096]
    float* out_sparse = (float*)d_out + 262144;        // [32,4096]

    float* Bws = (float*)d_ws;                                  // 6,291,456 B
    float* Aq  = (float*)((char*)d_ws + 6291456);               //    49,152 B
    short* W2T = (short*)((char*)d_ws + 6291456 + 49152);       //   147,456 B

    hipLaunchKernelGGL(prep_w2t,            dim3(288), dim3(256), 0, stream, W2, W2T);
    hipLaunchKernelGGL(ab_kernel,           dim3(258), dim3(384), 0, stream, doc, query, W1, Bws, Aq);
    hipLaunchKernelGGL(dense_sparse_kernel, dim3(256), dim3(256), 0, stream, query, doc, sparse, out_dense, out_sparse);
    hipLaunchKernelGGL(main_kernel,         dim3(256), dim3(512), 0, stream,
                       Aq, Bws, W1, b1, b2, W3, b3, sparse, W2T, out_dense, out_final);
}

// Round 5
// 638.126 us; speedup vs baseline: 1.3147x; 1.3147x over previous
//
#include <hip/hip_runtime.h>
#include <hip/hip_bf16.h>

typedef __attribute__((ext_vector_type(4))) float f32x4;
typedef __attribute__((ext_vector_type(8))) short bf16x8;

__device__ __forceinline__ short f2bf(float x){
    __hip_bfloat16 h = __float2bfloat16(x);
    return __builtin_bit_cast(short, h);
}
__device__ __forceinline__ float bf2f(short x){
    unsigned int u = ((unsigned int)(unsigned short)x) << 16;
    return __builtin_bit_cast(float, u);
}

// ---------------------------------------------------------------- prep: tiled bf16 weights
// W2Tt  [9216 chunks of 8]:  chunk=(s*12+t)*64+lane -> W2[k][n],  n=t*16+(lane&15), k=s*32+((lane>>4)&3)*8+j,  s<12,t<12
// W1aT/W1bT [2304+... 288 tile-chunks each]: chunk=(s*24+t)*64+lane -> W1[k(+384)][n], s<12, t<24
__global__ void prep_kernel(const float* __restrict__ W1, const float* __restrict__ W2,
                            short* __restrict__ W2Tt, short* __restrict__ W1aT,
                            short* __restrict__ W1bT){
    int i = blockIdx.x*256 + threadIdx.x;           // 368640 total = 1440*256 exactly
    if (i < 73728){
        int j = i & 7, c = i >> 3;
        int lane = c & 63, st = c >> 6;             // st < 144
        int s = st/12, t = st%12;
        int n = t*16 + (lane&15), k = s*32 + ((lane>>4)&3)*8 + j;
        W2Tt[i] = f2bf(W2[k*192 + n]);
    } else {
        int i2 = i - 73728;                         // i2 < 294912
        int part = i2 / 147456;                     // 0 = A (query side), 1 = B (doc side)
        int o = i2 % 147456;
        int j = o & 7, c = o >> 3;
        int lane = c & 63, st = c >> 6;             // st < 288
        int s = st/24, t = st%24;                   // s < 12, t < 24
        int n = t*16 + (lane&15), k = s*32 + ((lane>>4)&3)*8 + j;   // n<384, k<384
        short v = f2bf(W1[(part*384 + k)*384 + n]);
        if (part) W1bT[o] = v; else W1aT[o] = v;
    }
}

// ---------------------------------------------------------------- ab: MFMA GEMM
// blocks 0..255: Bws(bf16)[r0..r0+15] = doc rows @ W1b;  blocks 256..257: Aq(f32) = query @ W1a + b1.
// 256 thr = 4 waves; wave w owns n-tiles w*6..w*6+5 (96 cols).
__global__ __launch_bounds__(256)
void ab_kernel(const float* __restrict__ doc, const float* __restrict__ query,
               const short* __restrict__ W1aT, const short* __restrict__ W1bT,
               const float* __restrict__ b1,
               short* __restrict__ Bws, float* __restrict__ Aq){
    const int b = blockIdx.x, tid = threadIdx.x;
    const int w = tid >> 6, lane = tid & 63;
    const int cl = lane & 15, quad = lane >> 4;
    const float* src; const short* wt; int r0; bool isA;
    if (b < 256){ r0 = b*16;       src = doc;   wt = W1bT; isA = false; }
    else        { r0 = (b-256)*16; src = query; wt = W1aT; isA = true;  }

    f32x4 acc[6];
    #pragma unroll
    for (int t=0;t<6;t++) acc[t] = (f32x4){0.f,0.f,0.f,0.f};

    #pragma unroll
    for (int s=0;s<12;s++){
        const float* ap = src + (r0+cl)*384 + s*32 + quad*8;
        const f32x4 a0 = *(const f32x4*)ap;
        const f32x4 a1 = *(const f32x4*)(ap+4);
        bf16x8 af;
        #pragma unroll
        for (int j=0;j<4;j++){ af[j] = f2bf(a0[j]); af[4+j] = f2bf(a1[j]); }
        #pragma unroll
        for (int tt=0;tt<6;tt++){
            const bf16x8 bf_ = *(const bf16x8*)(wt + ((s*24 + w*6 + tt)*64 + lane)*8);
            acc[tt] = __builtin_amdgcn_mfma_f32_16x16x32_bf16(af, bf_, acc[tt], 0, 0, 0);
        }
    }
    // D layout: col=lane&15, row=quad*4+r
    #pragma unroll
    for (int tt=0;tt<6;tt++){
        const int col = (w*6+tt)*16 + cl;
        if (isA){
            const float b1v = b1[col];
            #pragma unroll
            for (int r=0;r<4;r++)
                Aq[(r0 + quad*4 + r)*384 + col] = acc[tt][r] + b1v;
        } else {
            #pragma unroll
            for (int r=0;r<4;r++)
                Bws[(r0 + quad*4 + r)*384 + col] = f2bf(acc[tt][r]);
        }
    }
}

// ---------------------------------------------------------------- dense scores + sparse copy
// (unchanged — known good from round 2)
__global__ void dense_sparse_kernel(const float* __restrict__ query, const float* __restrict__ doc,
                                    const float* __restrict__ sparse, float* __restrict__ out_dense,
                                    float* __restrict__ out_sparse){
    __shared__ float ldsq[32*388];
    __shared__ float ldsd[16*388];
    const int tid = threadIdx.x, d0 = blockIdx.x*16;
    #pragma unroll
    for (int i=0;i<12;i++){ int idx = tid + i*256; int row = idx/96, c4 = idx%96;
        *(f32x4*)(ldsq + row*388 + c4*4) = *(const f32x4*)(query + row*384 + c4*4); }
    #pragma unroll
    for (int i=0;i<6;i++){ int idx = tid + i*256; int row = idx/96, c4 = idx%96;
        *(f32x4*)(ldsd + row*388 + c4*4) = *(const f32x4*)(doc + (d0+row)*384 + c4*4); }
    __syncthreads();
    const int q = tid>>3, dg = tid&7;
    float acc0 = 0.0f, acc1 = 0.0f;
    #pragma unroll 4
    for (int k=0;k<384;k++){
        float qv = ldsq[q*388 + k];
        acc0 += qv*ldsd[dg*388 + k];
        acc1 += qv*ldsd[(dg+8)*388 + k];
    }
    out_dense[q*4096 + d0 + dg]     = acc0;
    out_dense[q*4096 + d0 + dg + 8] = acc1;
    if (tid < 128){
        int qq = tid>>2, c4 = tid&3;
        *(f32x4*)(out_sparse + qq*4096 + d0 + c4*4) = *(const f32x4*)(sparse + qq*4096 + d0 + c4*4);
    }
}

// ---------------------------------------------------------------- main fused MLP kernel
// 256 blocks x 512 thr. W2Tt resident in LDS in MFMA-tile order (73728 shorts = 147,456 B,
// conflict-free: wave-uniform base + lane*16). afrag built per-kstep, consumed immediately.
__global__ __launch_bounds__(512, 2)
void main_kernel(const float* __restrict__ Aq, const short* __restrict__ Bws,
                 const float* __restrict__ W1,
                 const float* __restrict__ b2, const float* __restrict__ W3,
                 const float* __restrict__ b3, const float* __restrict__ sparse,
                 const short* __restrict__ W2Tt, const float* __restrict__ dense_in,
                 float* __restrict__ out_final){
    __shared__ short lw[73728];                      // 147,456 bytes
    const int tid = threadIdx.x;
    #pragma unroll
    for (int i=0;i<18;i++){                          // 9216 x 16B linear copy
        int idx = tid + i*512;
        *(bf16x8*)(lw + idx*8) = *(const bf16x8*)(W2Tt + idx*8);
    }
    __syncthreads();                                 // only barrier

    const int lane = tid & 63, w = tid >> 6;
    const int cl = lane & 15, quad = lane >> 4;
    float b2r[12], w3r[12];
    #pragma unroll
    for (int t=0;t<12;t++){ b2r[t] = b2[t*16 + cl]; w3r[t] = W3[t*16 + cl]; }
    const float b3v = b3[0];
    const float* w1c = W1 + 768*384;
    const float* w1d = W1 + 769*384;

    for (int t4=0; t4<4; t4++){
        const int R0 = blockIdx.x*512 + t4*128 + w*16;   // 16 rows: 16 q's of one doc
        const int dcol = R0 >> 5;
        const int q0 = R0 & 31;
        const int q = q0 + cl;
        const float dsv = dense_in[q*4096 + dcol];
        const float ssv = sparse[q*4096 + dcol];

        f32x4 acc[12];
        #pragma unroll
        for (int t=0;t<12;t++) acc[t] = (f32x4){0.f,0.f,0.f,0.f};

        #pragma unroll
        for (int s=0;s<12;s++){
            const int k0 = s*32 + quad*8;
            // layer 1 for this kstep, directly in A-fragment layout (b1 pre-folded into Aq)
            const f32x4 a0  = *(const f32x4*)(Aq + q*384 + k0);
            const f32x4 a1  = *(const f32x4*)(Aq + q*384 + k0 + 4);
            const bf16x8 bw = *(const bf16x8*)(Bws + dcol*384 + k0);
            const f32x4 wc0 = *(const f32x4*)(w1c + k0);
            const f32x4 wc1 = *(const f32x4*)(w1c + k0 + 4);
            const f32x4 wd0 = *(const f32x4*)(w1d + k0);
            const f32x4 wd1 = *(const f32x4*)(w1d + k0 + 4);
            bf16x8 fr;
            #pragma unroll
            for (int j=0;j<4;j++){
                float h = a0[j] + bf2f(bw[j]) + dsv*wc0[j] + ssv*wd0[j];
                fr[j] = f2bf(fmaxf(h, 0.0f));
            }
            #pragma unroll
            for (int j=0;j<4;j++){
                float h = a1[j] + bf2f(bw[4+j]) + dsv*wc1[j] + ssv*wd1[j];
                fr[4+j] = f2bf(fmaxf(h, 0.0f));
            }
            #pragma unroll
            for (int t=0;t<12;t++){
                const bf16x8 bfr = *(const bf16x8*)(lw + ((s*12 + t)*64 + lane)*8);
                acc[t] = __builtin_amdgcn_mfma_f32_16x16x32_bf16(fr, bfr, acc[t], 0, 0, 0);
            }
        }

        // layer 3 + sigmoid blend. D layout: col=lane&15 -> n, row=quad*4+r
        float p[4] = {0.f,0.f,0.f,0.f};
        #pragma unroll
        for (int t=0;t<12;t++){
            #pragma unroll
            for (int r=0;r<4;r++)
                p[r] += fmaxf(acc[t][r] + b2r[t], 0.0f) * w3r[t];
        }
        #pragma unroll
        for (int m=1; m<16; m<<=1){
            #pragma unroll
            for (int r=0;r<4;r++) p[r] += __shfl_xor(p[r], m);
        }
        if (cl == 0){
            #pragma unroll
            for (int r=0;r<4;r++){
                int qq = q0 + quad*4 + r;
                float logit = p[r] + b3v;
                float wgt = 1.0f/(1.0f + __expf(-logit));
                float dd = dense_in[qq*4096 + dcol];
                float ss = sparse[qq*4096 + dcol];
                out_final[qq*4096 + dcol] = wgt*dd + (1.0f - wgt)*ss;
            }
        }
    }
}

// ---------------------------------------------------------------- launch
extern "C" void kernel_launch(void* const* d_in, const int* in_sizes, int n_in,
                              void* d_out, int out_size, void* d_ws, size_t ws_size,
                              hipStream_t stream){
    const float* query  = (const float*)d_in[0];
    const float* doc    = (const float*)d_in[1];
    const float* sparse = (const float*)d_in[2];
    const float* W1     = (const float*)d_in[3];
    const float* b1     = (const float*)d_in[4];
    const float* W2     = (const float*)d_in[5];
    const float* b2     = (const float*)d_in[6];
    const float* W3     = (const float*)d_in[7];
    const float* b3     = (const float*)d_in[8];

    float* out_final  = (float*)d_out;                 // [32,4096]
    float* out_dense  = (float*)d_out + 131072;        // [32,4096]
    float* out_sparse = (float*)d_out + 262144;        // [32,4096]

    // workspace layout (16B-aligned), total 3,932,160 B (< 6.49 MB proven safe in round 2)
    short* Bws  = (short*)d_ws;                                   // 3,145,728 B  (bf16 [4096][384])
    float* Aq   = (float*)((char*)d_ws + 3145728);                //    49,152 B  (f32  [32][384])
    short* W2Tt = (short*)((char*)d_ws + 3194880);                //   147,456 B
    short* W1aT = (short*)((char*)d_ws + 3342336);                //   294,912 B
    short* W1bT = (short*)((char*)d_ws + 3637248);                //   294,912 B

    hipLaunchKernelGGL(prep_kernel,         dim3(1440), dim3(256), 0, stream, W1, W2, W2Tt, W1aT, W1bT);
    hipLaunchKernelGGL(ab_kernel,           dim3(258),  dim3(256), 0, stream, doc, query, W1aT, W1bT, b1, Bws, Aq);
    hipLaunchKernelGGL(dense_sparse_kernel, dim3(256),  dim3(256), 0, stream, query, doc, sparse, out_dense, out_sparse);
    hipLaunchKernelGGL(main_kernel,         dim3(256),  dim3(512), 0, stream,
                       Aq, Bws, W1, b2, W3, b3, sparse, W2Tt, out_dense, out_final);
}